// Round 21
// baseline (61.262 us; speedup 1.0000x reference)
//
#include <hip/hip_runtime.h>

#define Bn 4
#define Cn 64
#define Hn 64
#define Wn 64
#define TW 4    // pixels (w) per block; ONE pixel per wave
#define F1n 5
#define F2n 10

typedef _Float16 half4v __attribute__((ext_vector_type(4)));
typedef _Float16 half8v __attribute__((ext_vector_type(8)));
typedef float    f32x4  __attribute__((ext_vector_type(4)));
typedef float    f32x2  __attribute__((ext_vector_type(2)));

#define MROW 20   // halves per scrambled-M row (10 data + 6 zero K-pad + 4 unused)
#define R1S  52   // halves per R1h row: 45 data + 3 zero + 4 unused. 104B = 26-word
                  // stride -> 16 distinct bank starts (2-way = free); do NOT "fix"
                  // to 48/96B (period-4 bank aliasing, r19 regression).

// r20 base (52.9us, best) + division-free xs staging (isolated r19 piece:
// shifts/masks replace idx/40,idx%40 magic-muls; xs layout/content identical).
__global__ __launch_bounds__(256, 5) void cam_fused_kernel(
    const float* __restrict__ x, const float* __restrict__ pv,
    const float* __restrict__ w1, const float* __restrict__ b1,
    const float* __restrict__ w2, const float* __restrict__ b2,
    float* __restrict__ out)
{
    // smem union: phase1 xs[64*41] f32 (10.5KB);
    // phase2 R1h: 4 waves x 64 rows x R1S halves (6656B/wave);
    // phase3 Mh (64 x MROW halves) aliased into the wave's R1h slice.
    __shared__ __align__(16) unsigned smem[6656];
    __shared__ __align__(16) float pvt[TW * 64];    // pv tile [w][c]
    __shared__ __align__(16) float outs[64 * 5];    // [c][4] stride 5

    const int tid  = threadIdx.x;
    const int wave = tid >> 6;
    const int lane = tid & 63;        // = channel c in conv phase
    const int g    = lane >> 4;       // 16-lane k-group (0..3)
    const int r16  = lane & 15;

    const int blk = blockIdx.x;       // 0..4095
    const int b   = blk >> 10;
    const int rem = blk & 1023;
    const int h   = rem >> 4;
    const int w0  = (rem & 15) << 2;

    const int CHW = Cn * Hn * Wn;
    const int HW  = Hn * Wn;

    // ---- stage pv tile transposed: pvt[w][c] ----
    if (tid < 64) {
        const float4 v = *(const float4*)&pv[b * CHW + tid * HW + h * Wn + w0];
        pvt[0 * 64 + tid] = v.x;
        pvt[1 * 64 + tid] = v.y;
        pvt[2 * 64 + tid] = v.z;
        pvt[3 * 64 + tid] = v.w;
    }

    // ---- phase 1: stage x region, DIVISION-FREE: thread (c0 = tid>>3,
    //      r = (tid&7)*5 + m) covers channels c0 and c0+32; xs[c][r], r = i*8+j ----
    {
        float* xs = (float*)smem;
        const float* xb = x + b * CHW;
        const int c0  = tid >> 3;          // 0..31
        const int rb5 = (tid & 7) * 5;     // 0..35
        #pragma unroll
        for (int hf = 0; hf < 2; ++hf) {
            const int c = c0 + hf * 32;
            const float* xc = xb + c * HW;
            #pragma unroll
            for (int m = 0; m < 5; ++m) {
                const int r = rb5 + m;
                const int i = r >> 3, j = r & 7;
                const int hh = h - 2 + i, ww = w0 - 2 + j;
                float v = 0.f;
                if ((unsigned)hh < 64u && (unsigned)ww < 64u)
                    v = xc[hh * Wn + ww];
                xs[c * 41 + r] = v;
            }
        }
    }
    __syncthreads();

    const float L2E = 1.4426950408889634f;

    const bool rOK0 = (h >= 1);
    const bool rOK2 = (h <= 62);

    const int lw = wave;            // this wave's pixel (0..3)
    const int w  = w0 + lw;
    const bool cOK0 = (w >= 1);
    const bool cOK2 = (w <= 62);

    // ---- 5x5 patch from xs to registers ----
    float xp[5][5];
    {
        const float* xs = (const float*)smem;
        #pragma unroll
        for (int i = 0; i < 5; ++i)
            #pragma unroll
            for (int j = 0; j < 5; ++j)
                xp[i][j] = xs[lane * 41 + i * 8 + lw + j];
    }
    // all waves done with xs -> smem becomes R1h
    __syncthreads();

    _Float16* R1h = (_Float16*)smem + wave * 3328;   // 64 rows x R1S halves
    _Float16* Mh  = R1h;                              // phase-3 reuse (same wave)

    // ---- conv1 + relu, border-masked; packed-f32 pairs sharing weights ----
    float r1f[45];
    #pragma unroll
    for (int f = 0; f < F1n; ++f) {
        const float bias = b1[f];
        f32x2 p01[3];   // (ih, iw=0) and (ih, iw=1)
        #pragma unroll
        for (int ih = 0; ih < 3; ++ih) {
            f32x2 a2 = { bias, bias };
            #pragma unroll
            for (int i = 0; i < 3; ++i)
                #pragma unroll
                for (int j = 0; j < 3; ++j) {
                    const float wv = w1[f * 9 + i * 3 + j];
                    const f32x2 x2 = { xp[ih + i][j], xp[ih + i][1 + j] };
                    a2 = __builtin_elementwise_fma(x2, (f32x2){ wv, wv }, a2);
                }
            p01[ih] = a2;
        }
        f32x2 a22 = { bias, bias };   // (ih=0, iw=2) and (ih=1, iw=2)
        #pragma unroll
        for (int i = 0; i < 3; ++i)
            #pragma unroll
            for (int j = 0; j < 3; ++j) {
                const float wv = w1[f * 9 + i * 3 + j];
                const f32x2 x2 = { xp[i][2 + j], xp[1 + i][2 + j] };
                a22 = __builtin_elementwise_fma(x2, (f32x2){ wv, wv }, a22);
            }
        float a2s = bias;             // (ih=2, iw=2)
        #pragma unroll
        for (int i = 0; i < 3; ++i)
            #pragma unroll
            for (int j = 0; j < 3; ++j)
                a2s = fmaf(xp[2 + i][2 + j], w1[f * 9 + i * 3 + j], a2s);

        #pragma unroll
        for (int ih = 0; ih < 3; ++ih) {
            const bool rok = (ih == 0) ? rOK0 : (ih == 2) ? rOK2 : true;
            r1f[f * 9 + ih * 3 + 0] = (rok && cOK0) ? fmaxf(p01[ih].x, 0.f) : 0.f;
            r1f[f * 9 + ih * 3 + 1] = rok           ? fmaxf(p01[ih].y, 0.f) : 0.f;
        }
        r1f[f * 9 + 0 * 3 + 2] = (rOK0 && cOK2) ? fmaxf(a22.x, 0.f) : 0.f;
        r1f[f * 9 + 1 * 3 + 2] = cOK2           ? fmaxf(a22.y, 0.f) : 0.f;
        r1f[f * 9 + 2 * 3 + 2] = (rOK2 && cOK2) ? fmaxf(a2s,   0.f) : 0.f;
    }

    // ---- write own row (c = lane) of R1h as f16: 48 halves (45 + 3 zero) ----
    {
        _Float16 rh[48];
        #pragma unroll
        for (int q = 0; q < 45; ++q) rh[q] = (_Float16)r1f[q];
        rh[45] = (_Float16)0; rh[46] = (_Float16)0; rh[47] = (_Float16)0;
        #pragma unroll
        for (int s = 0; s < 12; ++s)
            *(half4v*)&R1h[lane * R1S + s * 4] = *(const half4v*)&rh[s * 4];
    }

    const half8v zf = { (_Float16)0, (_Float16)0, (_Float16)0, (_Float16)0,
                        (_Float16)0, (_Float16)0, (_Float16)0, (_Float16)0 };

    // ---- W2 B-frags (col = r16 = g-out, k = 8*g + j within chunk), one-time ----
    half8v wb[2];
    #pragma unroll
    for (int kc = 0; kc < 2; ++kc) {
        half8v t = zf;
        #pragma unroll
        for (int j = 0; j < 8; ++j) {
            const int q = kc * 32 + g * 8 + j;
            if (r16 < 10 && q < 45)
                t[j] = (_Float16)w2[r16 * 45 + q];
        }
        wb[kc] = t;
    }

    // ---- conv2 via MFMA: D[c][gout] = sum_q R1[c][q] * W2t[q][gout] ----
    f32x4 tacc[4];
    #pragma unroll
    for (int Mt = 0; Mt < 4; ++Mt) {
        const int arow = Mt * 16 + r16;
        const half4v a0 = *(const half4v*)&R1h[arow * R1S + g * 8];
        const half4v a1 = *(const half4v*)&R1h[arow * R1S + g * 8 + 4];
        const half8v fA0 = __builtin_shufflevector(a0, a1, 0, 1, 2, 3, 4, 5, 6, 7);
        half8v fA1 = zf;
        if (g < 2) {
            const half4v c0 = *(const half4v*)&R1h[arow * R1S + 32 + g * 8];
            const half4v c1 = *(const half4v*)&R1h[arow * R1S + 32 + g * 8 + 4];
            fA1 = __builtin_shufflevector(c0, c1, 0, 1, 2, 3, 4, 5, 6, 7);
        }
        f32x4 acc = __builtin_amdgcn_mfma_f32_16x16x32_f16(
            fA0, wb[0], (f32x4){0.f, 0.f, 0.f, 0.f}, 0, 0, 0);
        acc = __builtin_amdgcn_mfma_f32_16x16x32_f16(fA1, wb[1], acc, 0, 0, 0);
        tacc[Mt] = acc;
    }

    // ---- bias + reshape-scramble scatter from D layout, division-light:
    //      k = k0 + off, k0 = r16*64 + g*4 (one magic-div pair), off = Mt*16+j
    //      (compile-time div/mod); wrap-compare instead of per-k division. ----
    if (r16 < 10) {
        const float bias = b2[r16];
        const int k0 = r16 * 64 + g * 4;
        const int q0 = k0 / 10;
        const int r0 = k0 % 10;
        const int base = q0 * MROW + r0;
        #pragma unroll
        for (int Mt = 0; Mt < 4; ++Mt)
            #pragma unroll
            for (int j = 0; j < 4; ++j) {
                const int off = Mt * 16 + j;            // compile-time
                const int a = off / 10, t = off % 10;   // compile-time
                const int wrap = (r0 >= 10 - t) ? 1 : 0;
                const int addr = base + a * MROW + t + wrap * (MROW - 10);
                Mh[addr] = (_Float16)(tacc[Mt][j] + bias);
            }
    }
    // zero K-pad halves 10..15 of each M row (after R1h fully consumed)
    {
        unsigned* MhW = (unsigned*)Mh;
        MhW[lane * (MROW / 2) + 5] = 0u;
        MhW[lane * (MROW / 2) + 6] = 0u;
        MhW[lane * (MROW / 2) + 7] = 0u;
    }

    // ---- gram fragments from Mh ----
    half8v fa[4];
    #pragma unroll
    for (int T = 0; T < 4; ++T) {
        const int base = (T * 16 + r16) * MROW + (g & 1) * 8;
        const half4v lo = *(const half4v*)&Mh[base];
        const half4v hi = *(const half4v*)&Mh[base + 4];
        const half8v f = __builtin_shufflevector(lo, hi, 0, 1, 2, 3, 4, 5, 6, 7);
        fa[T] = (g < 2) ? f : zf;
    }

    // pv at this lane's cols: pvf[R][j] = pv[16R + 4g + j]
    f32x4 pvf[4];
    #pragma unroll
    for (int R = 0; R < 4; ++R)
        pvf[R] = *(const f32x4*)&pvt[lw * 64 + R * 16 + g * 4];

    // ---- per-C streaming gram + constant-shift softmax + PV ----
    const float nmc = -30.0f * L2E;
    float oval = 0.f;
    #pragma unroll
    for (int C = 0; C < 4; ++C) {
        f32x4 accC[4];
        #pragma unroll
        for (int R = 0; R < 4; ++R)
            accC[R] = __builtin_amdgcn_mfma_f32_16x16x32_f16(
                fa[R], fa[C], (f32x4){0.f, 0.f, 0.f, 0.f}, 0, 0, 0);

        f32x2 s2 = { 0.f, 0.f }, d2 = { 0.f, 0.f };
        #pragma unroll
        for (int R = 0; R < 4; ++R) {
            const float e0 = __builtin_amdgcn_exp2f(fmaf(accC[R][0], L2E, nmc));
            const float e1 = __builtin_amdgcn_exp2f(fmaf(accC[R][1], L2E, nmc));
            const float e2 = __builtin_amdgcn_exp2f(fmaf(accC[R][2], L2E, nmc));
            const float e3 = __builtin_amdgcn_exp2f(fmaf(accC[R][3], L2E, nmc));
            const f32x2 elo = { e0, e1 }, ehi = { e2, e3 };
            const f32x2 plo = { pvf[R][0], pvf[R][1] };
            const f32x2 phi = { pvf[R][2], pvf[R][3] };
            s2 += elo;
            s2 += ehi;
            d2 = __builtin_elementwise_fma(elo, plo, d2);
            d2 = __builtin_elementwise_fma(ehi, phi, d2);
        }
        float s = s2.x + s2.y;
        float d = d2.x + d2.y;
        s += __shfl_xor(s, 16);
        s += __shfl_xor(s, 32);
        d += __shfl_xor(d, 16);
        d += __shfl_xor(d, 32);
        if (g == C) oval = d / s;   // kept row 16C + r16 == lane
    }
    outs[lane * 5 + lw] = oval;

    __syncthreads();   // outs columns come from all waves

    // ---- output write: [64][4] tile -> out[b, c, h, w0..w0+3] ----
    if (tid < 64) {
        float4 v;
        v.x = outs[tid * 5 + 0];
        v.y = outs[tid * 5 + 1];
        v.z = outs[tid * 5 + 2];
        v.w = outs[tid * 5 + 3];
        *(float4*)&out[b * CHW + tid * HW + h * Wn + w0] = v;
    }
}

extern "C" void kernel_launch(void* const* d_in, const int* in_sizes, int n_in,
                              void* d_out, int out_size, void* d_ws, size_t ws_size,
                              hipStream_t stream) {
    const float* x  = (const float*)d_in[0];
    const float* pv = (const float*)d_in[1];
    const float* w1 = (const float*)d_in[2];
    const float* b1 = (const float*)d_in[3];
    const float* w2 = (const float*)d_in[4];
    const float* b2 = (const float*)d_in[5];
    float* out = (float*)d_out;

    dim3 grid(Bn * Hn * (Wn / TW));   // 4096
    dim3 block(256);
    hipLaunchKernelGGL(cam_fused_kernel, grid, block, 0, stream,
                       x, pv, w1, b1, w2, b2, out);
}

// Round 22
// 51.449 us; speedup vs baseline: 1.1907x; 1.1907x over previous
//
#include <hip/hip_runtime.h>

#define Bn 4
#define Cn 64
#define Hn 64
#define Wn 64
#define TW 4    // pixels (w) per block; ONE pixel per wave
#define F1n 5
#define F2n 10

typedef _Float16 half4v __attribute__((ext_vector_type(4)));
typedef _Float16 half8v __attribute__((ext_vector_type(8)));
typedef float    f32x4  __attribute__((ext_vector_type(4)));
typedef float    f32x2  __attribute__((ext_vector_type(2)));

#define MROW 20   // halves per scrambled-M row (10 data + 6 zero K-pad + 4 unused)
#define R1S  52   // halves per R1h row: 45 data + 3 zero + 4 unused. 104B = 26-word
                  // stride -> 16 distinct bank starts (2-way = free); do NOT "fix"
                  // to 48/96B (period-4 bank aliasing, r19 regression).

// r20 base (52.9us, best). Staging keeps r20's exact thread->element map
// (coalesced; r21's "div-free" remap broke coalescing, 61us) but replaces
// per-iteration magic-divs with one div + incremental (c+=6, r+=16, wrap).
__global__ __launch_bounds__(256, 5) void cam_fused_kernel(
    const float* __restrict__ x, const float* __restrict__ pv,
    const float* __restrict__ w1, const float* __restrict__ b1,
    const float* __restrict__ w2, const float* __restrict__ b2,
    float* __restrict__ out)
{
    // smem union: phase1 xs[64*41] f32 (10.5KB);
    // phase2 R1h: 4 waves x 64 rows x R1S halves (6656B/wave);
    // phase3 Mh (64 x MROW halves) aliased into the wave's R1h slice.
    __shared__ __align__(16) unsigned smem[6656];
    __shared__ __align__(16) float pvt[TW * 64];    // pv tile [w][c]
    __shared__ __align__(16) float outs[64 * 5];    // [c][4] stride 5

    const int tid  = threadIdx.x;
    const int wave = tid >> 6;
    const int lane = tid & 63;        // = channel c in conv phase
    const int g    = lane >> 4;       // 16-lane k-group (0..3)
    const int r16  = lane & 15;

    const int blk = blockIdx.x;       // 0..4095
    const int b   = blk >> 10;
    const int rem = blk & 1023;
    const int h   = rem >> 4;
    const int w0  = (rem & 15) << 2;

    const int CHW = Cn * Hn * Wn;
    const int HW  = Hn * Wn;

    // ---- stage pv tile transposed: pvt[w][c] ----
    if (tid < 64) {
        const float4 v = *(const float4*)&pv[b * CHW + tid * HW + h * Wn + w0];
        pvt[0 * 64 + tid] = v.x;
        pvt[1 * 64 + tid] = v.y;
        pvt[2 * 64 + tid] = v.z;
        pvt[3 * 64 + tid] = v.w;
    }

    // ---- phase 1: stage x region into smem-as-xs: [c][5][8], stride 41.
    //      Same (c,r) assignment as idx=tid+256k, c=idx/40, r=idx%40 — but
    //      ONE division then incremental update (256 = 6*40 + 16). ----
    {
        float* xs = (float*)smem;
        const float* xb = x + b * CHW;
        int c = tid / 40;
        int r = tid - c * 40;
        #pragma unroll
        for (int k = 0; k < 10; ++k) {   // 64*40 = 2560 = 256*10 exactly
            const int i = r >> 3, j = r & 7;
            const int hh = h - 2 + i, ww = w0 - 2 + j;
            float v = 0.f;
            if ((unsigned)hh < 64u && (unsigned)ww < 64u)
                v = xb[c * HW + hh * Wn + ww];
            xs[c * 41 + r] = v;
            c += 6; r += 16;
            if (r >= 40) { r -= 40; c += 1; }
        }
    }
    __syncthreads();

    const float L2E = 1.4426950408889634f;

    const bool rOK0 = (h >= 1);
    const bool rOK2 = (h <= 62);

    const int lw = wave;            // this wave's pixel (0..3)
    const int w  = w0 + lw;
    const bool cOK0 = (w >= 1);
    const bool cOK2 = (w <= 62);

    // ---- 5x5 patch from xs to registers ----
    float xp[5][5];
    {
        const float* xs = (const float*)smem;
        #pragma unroll
        for (int i = 0; i < 5; ++i)
            #pragma unroll
            for (int j = 0; j < 5; ++j)
                xp[i][j] = xs[lane * 41 + i * 8 + lw + j];
    }
    // all waves done with xs -> smem becomes R1h
    __syncthreads();

    _Float16* R1h = (_Float16*)smem + wave * 3328;   // 64 rows x R1S halves
    _Float16* Mh  = R1h;                              // phase-3 reuse (same wave)

    // ---- conv1 + relu, border-masked; packed-f32 pairs sharing weights ----
    float r1f[45];
    #pragma unroll
    for (int f = 0; f < F1n; ++f) {
        const float bias = b1[f];
        f32x2 p01[3];   // (ih, iw=0) and (ih, iw=1)
        #pragma unroll
        for (int ih = 0; ih < 3; ++ih) {
            f32x2 a2 = { bias, bias };
            #pragma unroll
            for (int i = 0; i < 3; ++i)
                #pragma unroll
                for (int j = 0; j < 3; ++j) {
                    const float wv = w1[f * 9 + i * 3 + j];
                    const f32x2 x2 = { xp[ih + i][j], xp[ih + i][1 + j] };
                    a2 = __builtin_elementwise_fma(x2, (f32x2){ wv, wv }, a2);
                }
            p01[ih] = a2;
        }
        f32x2 a22 = { bias, bias };   // (ih=0, iw=2) and (ih=1, iw=2)
        #pragma unroll
        for (int i = 0; i < 3; ++i)
            #pragma unroll
            for (int j = 0; j < 3; ++j) {
                const float wv = w1[f * 9 + i * 3 + j];
                const f32x2 x2 = { xp[i][2 + j], xp[1 + i][2 + j] };
                a22 = __builtin_elementwise_fma(x2, (f32x2){ wv, wv }, a22);
            }
        float a2s = bias;             // (ih=2, iw=2)
        #pragma unroll
        for (int i = 0; i < 3; ++i)
            #pragma unroll
            for (int j = 0; j < 3; ++j)
                a2s = fmaf(xp[2 + i][2 + j], w1[f * 9 + i * 3 + j], a2s);

        #pragma unroll
        for (int ih = 0; ih < 3; ++ih) {
            const bool rok = (ih == 0) ? rOK0 : (ih == 2) ? rOK2 : true;
            r1f[f * 9 + ih * 3 + 0] = (rok && cOK0) ? fmaxf(p01[ih].x, 0.f) : 0.f;
            r1f[f * 9 + ih * 3 + 1] = rok           ? fmaxf(p01[ih].y, 0.f) : 0.f;
        }
        r1f[f * 9 + 0 * 3 + 2] = (rOK0 && cOK2) ? fmaxf(a22.x, 0.f) : 0.f;
        r1f[f * 9 + 1 * 3 + 2] = cOK2           ? fmaxf(a22.y, 0.f) : 0.f;
        r1f[f * 9 + 2 * 3 + 2] = (rOK2 && cOK2) ? fmaxf(a2s,   0.f) : 0.f;
    }

    // ---- write own row (c = lane) of R1h as f16: 48 halves (45 + 3 zero) ----
    {
        _Float16 rh[48];
        #pragma unroll
        for (int q = 0; q < 45; ++q) rh[q] = (_Float16)r1f[q];
        rh[45] = (_Float16)0; rh[46] = (_Float16)0; rh[47] = (_Float16)0;
        #pragma unroll
        for (int s = 0; s < 12; ++s)
            *(half4v*)&R1h[lane * R1S + s * 4] = *(const half4v*)&rh[s * 4];
    }

    const half8v zf = { (_Float16)0, (_Float16)0, (_Float16)0, (_Float16)0,
                        (_Float16)0, (_Float16)0, (_Float16)0, (_Float16)0 };

    // ---- W2 B-frags (col = r16 = g-out, k = 8*g + j within chunk), one-time ----
    half8v wb[2];
    #pragma unroll
    for (int kc = 0; kc < 2; ++kc) {
        half8v t = zf;
        #pragma unroll
        for (int j = 0; j < 8; ++j) {
            const int q = kc * 32 + g * 8 + j;
            if (r16 < 10 && q < 45)
                t[j] = (_Float16)w2[r16 * 45 + q];
        }
        wb[kc] = t;
    }

    // ---- conv2 via MFMA: D[c][gout] = sum_q R1[c][q] * W2t[q][gout] ----
    f32x4 tacc[4];
    #pragma unroll
    for (int Mt = 0; Mt < 4; ++Mt) {
        const int arow = Mt * 16 + r16;
        const half4v a0 = *(const half4v*)&R1h[arow * R1S + g * 8];
        const half4v a1 = *(const half4v*)&R1h[arow * R1S + g * 8 + 4];
        const half8v fA0 = __builtin_shufflevector(a0, a1, 0, 1, 2, 3, 4, 5, 6, 7);
        half8v fA1 = zf;
        if (g < 2) {
            const half4v c0 = *(const half4v*)&R1h[arow * R1S + 32 + g * 8];
            const half4v c1 = *(const half4v*)&R1h[arow * R1S + 32 + g * 8 + 4];
            fA1 = __builtin_shufflevector(c0, c1, 0, 1, 2, 3, 4, 5, 6, 7);
        }
        f32x4 acc = __builtin_amdgcn_mfma_f32_16x16x32_f16(
            fA0, wb[0], (f32x4){0.f, 0.f, 0.f, 0.f}, 0, 0, 0);
        acc = __builtin_amdgcn_mfma_f32_16x16x32_f16(fA1, wb[1], acc, 0, 0, 0);
        tacc[Mt] = acc;
    }

    // ---- bias + reshape-scramble scatter from D layout, division-light ----
    if (r16 < 10) {
        const float bias = b2[r16];
        const int k0 = r16 * 64 + g * 4;
        const int q0 = k0 / 10;
        const int r0 = k0 % 10;
        const int base = q0 * MROW + r0;
        #pragma unroll
        for (int Mt = 0; Mt < 4; ++Mt)
            #pragma unroll
            for (int j = 0; j < 4; ++j) {
                const int off = Mt * 16 + j;            // compile-time
                const int a = off / 10, t = off % 10;   // compile-time
                const int wrap = (r0 >= 10 - t) ? 1 : 0;
                const int addr = base + a * MROW + t + wrap * (MROW - 10);
                Mh[addr] = (_Float16)(tacc[Mt][j] + bias);
            }
    }
    // zero K-pad halves 10..15 of each M row (after R1h fully consumed)
    {
        unsigned* MhW = (unsigned*)Mh;
        MhW[lane * (MROW / 2) + 5] = 0u;
        MhW[lane * (MROW / 2) + 6] = 0u;
        MhW[lane * (MROW / 2) + 7] = 0u;
    }

    // ---- gram fragments from Mh ----
    half8v fa[4];
    #pragma unroll
    for (int T = 0; T < 4; ++T) {
        const int base = (T * 16 + r16) * MROW + (g & 1) * 8;
        const half4v lo = *(const half4v*)&Mh[base];
        const half4v hi = *(const half4v*)&Mh[base + 4];
        const half8v f = __builtin_shufflevector(lo, hi, 0, 1, 2, 3, 4, 5, 6, 7);
        fa[T] = (g < 2) ? f : zf;
    }

    // pv at this lane's cols: pvf[R][j] = pv[16R + 4g + j]
    f32x4 pvf[4];
    #pragma unroll
    for (int R = 0; R < 4; ++R)
        pvf[R] = *(const f32x4*)&pvt[lw * 64 + R * 16 + g * 4];

    // ---- per-C streaming gram + constant-shift softmax + PV ----
    const float nmc = -30.0f * L2E;
    float oval = 0.f;
    #pragma unroll
    for (int C = 0; C < 4; ++C) {
        f32x4 accC[4];
        #pragma unroll
        for (int R = 0; R < 4; ++R)
            accC[R] = __builtin_amdgcn_mfma_f32_16x16x32_f16(
                fa[R], fa[C], (f32x4){0.f, 0.f, 0.f, 0.f}, 0, 0, 0);

        f32x2 s2 = { 0.f, 0.f }, d2 = { 0.f, 0.f };
        #pragma unroll
        for (int R = 0; R < 4; ++R) {
            const float e0 = __builtin_amdgcn_exp2f(fmaf(accC[R][0], L2E, nmc));
            const float e1 = __builtin_amdgcn_exp2f(fmaf(accC[R][1], L2E, nmc));
            const float e2 = __builtin_amdgcn_exp2f(fmaf(accC[R][2], L2E, nmc));
            const float e3 = __builtin_amdgcn_exp2f(fmaf(accC[R][3], L2E, nmc));
            const f32x2 elo = { e0, e1 }, ehi = { e2, e3 };
            const f32x2 plo = { pvf[R][0], pvf[R][1] };
            const f32x2 phi = { pvf[R][2], pvf[R][3] };
            s2 += elo;
            s2 += ehi;
            d2 = __builtin_elementwise_fma(elo, plo, d2);
            d2 = __builtin_elementwise_fma(ehi, phi, d2);
        }
        float s = s2.x + s2.y;
        float d = d2.x + d2.y;
        s += __shfl_xor(s, 16);
        s += __shfl_xor(s, 32);
        d += __shfl_xor(d, 16);
        d += __shfl_xor(d, 32);
        if (g == C) oval = d / s;   // kept row 16C + r16 == lane
    }
    outs[lane * 5 + lw] = oval;

    __syncthreads();   // outs columns come from all waves

    // ---- output write: [64][4] tile -> out[b, c, h, w0..w0+3] ----
    if (tid < 64) {
        float4 v;
        v.x = outs[tid * 5 + 0];
        v.y = outs[tid * 5 + 1];
        v.z = outs[tid * 5 + 2];
        v.w = outs[tid * 5 + 3];
        *(float4*)&out[b * CHW + tid * HW + h * Wn + w0] = v;
    }
}

extern "C" void kernel_launch(void* const* d_in, const int* in_sizes, int n_in,
                              void* d_out, int out_size, void* d_ws, size_t ws_size,
                              hipStream_t stream) {
    const float* x  = (const float*)d_in[0];
    const float* pv = (const float*)d_in[1];
    const float* w1 = (const float*)d_in[2];
    const float* b1 = (const float*)d_in[3];
    const float* w2 = (const float*)d_in[4];
    const float* b2 = (const float*)d_in[5];
    float* out = (float*)d_out;

    dim3 grid(Bn * Hn * (Wn / TW));   // 4096
    dim3 block(256);
    hipLaunchKernelGGL(cam_fused_kernel, grid, block, 0, stream,
                       x, pv, w1, b1, w2, b2, out);
}

// Round 23
// 39.812 us; speedup vs baseline: 1.5388x; 1.2923x over previous
//
#include <hip/hip_runtime.h>

#define Bn 4
#define Cn 64
#define Hn 64
#define Wn 64
#define TW 4    // pixels (w) per block; ONE pixel per wave
#define F1n 5
#define F2n 10

typedef _Float16 half4v __attribute__((ext_vector_type(4)));
typedef _Float16 half8v __attribute__((ext_vector_type(8)));
typedef float    f32x4  __attribute__((ext_vector_type(4)));
typedef float    f32x2  __attribute__((ext_vector_type(2)));

#define MROW 20   // halves per scrambled-M row (10 data + 6 zero K-pad + 4 unused)
#define R1S  52   // halves per R1h row: 45 data + 3 zero + 4 unused. 104B = 26-word
                  // stride -> 16 distinct bank starts (2-way = free); do NOT "fix"
                  // to 48/96B (period-4 bank aliasing, r19 regression).

// r22 base (51.4us, best) + XCD-aware block swizzle: dispatch d -> XCD d%8;
// work = (d%8)*512 + d/8 gives each XCD a contiguous b/h chunk so halo rows
// (h+-2) are L2-resident (557KB/XCD << 4MB). Bijective: 4096 = 8*512.
__global__ __launch_bounds__(256, 5) void cam_fused_kernel(
    const float* __restrict__ x, const float* __restrict__ pv,
    const float* __restrict__ w1, const float* __restrict__ b1,
    const float* __restrict__ w2, const float* __restrict__ b2,
    float* __restrict__ out)
{
    // smem union: phase1 xs[64*41] f32 (10.5KB);
    // phase2 R1h: 4 waves x 64 rows x R1S halves (6656B/wave);
    // phase3 Mh (64 x MROW halves) aliased into the wave's R1h slice.
    __shared__ __align__(16) unsigned smem[6656];
    __shared__ __align__(16) float pvt[TW * 64];    // pv tile [w][c]
    __shared__ __align__(16) float outs[64 * 5];    // [c][4] stride 5

    const int tid  = threadIdx.x;
    const int wave = tid >> 6;
    const int lane = tid & 63;        // = channel c in conv phase
    const int g    = lane >> 4;       // 16-lane k-group (0..3)
    const int r16  = lane & 15;

    // XCD-aware swizzle (T1): contiguous 512-block work chunk per XCD.
    const int blk = ((blockIdx.x & 7) << 9) + (blockIdx.x >> 3);   // 0..4095
    const int b   = blk >> 10;
    const int rem = blk & 1023;
    const int h   = rem >> 4;
    const int w0  = (rem & 15) << 2;

    const int CHW = Cn * Hn * Wn;
    const int HW  = Hn * Wn;

    // ---- stage pv tile transposed: pvt[w][c] ----
    if (tid < 64) {
        const float4 v = *(const float4*)&pv[b * CHW + tid * HW + h * Wn + w0];
        pvt[0 * 64 + tid] = v.x;
        pvt[1 * 64 + tid] = v.y;
        pvt[2 * 64 + tid] = v.z;
        pvt[3 * 64 + tid] = v.w;
    }

    // ---- phase 1: stage x region into smem-as-xs: [c][5][8], stride 41.
    //      Same (c,r) assignment as idx=tid+256k, c=idx/40, r=idx%40 — but
    //      ONE division then incremental update (256 = 6*40 + 16). ----
    {
        float* xs = (float*)smem;
        const float* xb = x + b * CHW;
        int c = tid / 40;
        int r = tid - c * 40;
        #pragma unroll
        for (int k = 0; k < 10; ++k) {   // 64*40 = 2560 = 256*10 exactly
            const int i = r >> 3, j = r & 7;
            const int hh = h - 2 + i, ww = w0 - 2 + j;
            float v = 0.f;
            if ((unsigned)hh < 64u && (unsigned)ww < 64u)
                v = xb[c * HW + hh * Wn + ww];
            xs[c * 41 + r] = v;
            c += 6; r += 16;
            if (r >= 40) { r -= 40; c += 1; }
        }
    }
    __syncthreads();

    const float L2E = 1.4426950408889634f;

    const bool rOK0 = (h >= 1);
    const bool rOK2 = (h <= 62);

    const int lw = wave;            // this wave's pixel (0..3)
    const int w  = w0 + lw;
    const bool cOK0 = (w >= 1);
    const bool cOK2 = (w <= 62);

    // ---- 5x5 patch from xs to registers ----
    float xp[5][5];
    {
        const float* xs = (const float*)smem;
        #pragma unroll
        for (int i = 0; i < 5; ++i)
            #pragma unroll
            for (int j = 0; j < 5; ++j)
                xp[i][j] = xs[lane * 41 + i * 8 + lw + j];
    }
    // all waves done with xs -> smem becomes R1h
    __syncthreads();

    _Float16* R1h = (_Float16*)smem + wave * 3328;   // 64 rows x R1S halves
    _Float16* Mh  = R1h;                              // phase-3 reuse (same wave)

    // ---- conv1 + relu, border-masked; packed-f32 pairs sharing weights ----
    float r1f[45];
    #pragma unroll
    for (int f = 0; f < F1n; ++f) {
        const float bias = b1[f];
        f32x2 p01[3];   // (ih, iw=0) and (ih, iw=1)
        #pragma unroll
        for (int ih = 0; ih < 3; ++ih) {
            f32x2 a2 = { bias, bias };
            #pragma unroll
            for (int i = 0; i < 3; ++i)
                #pragma unroll
                for (int j = 0; j < 3; ++j) {
                    const float wv = w1[f * 9 + i * 3 + j];
                    const f32x2 x2 = { xp[ih + i][j], xp[ih + i][1 + j] };
                    a2 = __builtin_elementwise_fma(x2, (f32x2){ wv, wv }, a2);
                }
            p01[ih] = a2;
        }
        f32x2 a22 = { bias, bias };   // (ih=0, iw=2) and (ih=1, iw=2)
        #pragma unroll
        for (int i = 0; i < 3; ++i)
            #pragma unroll
            for (int j = 0; j < 3; ++j) {
                const float wv = w1[f * 9 + i * 3 + j];
                const f32x2 x2 = { xp[i][2 + j], xp[1 + i][2 + j] };
                a22 = __builtin_elementwise_fma(x2, (f32x2){ wv, wv }, a22);
            }
        float a2s = bias;             // (ih=2, iw=2)
        #pragma unroll
        for (int i = 0; i < 3; ++i)
            #pragma unroll
            for (int j = 0; j < 3; ++j)
                a2s = fmaf(xp[2 + i][2 + j], w1[f * 9 + i * 3 + j], a2s);

        #pragma unroll
        for (int ih = 0; ih < 3; ++ih) {
            const bool rok = (ih == 0) ? rOK0 : (ih == 2) ? rOK2 : true;
            r1f[f * 9 + ih * 3 + 0] = (rok && cOK0) ? fmaxf(p01[ih].x, 0.f) : 0.f;
            r1f[f * 9 + ih * 3 + 1] = rok           ? fmaxf(p01[ih].y, 0.f) : 0.f;
        }
        r1f[f * 9 + 0 * 3 + 2] = (rOK0 && cOK2) ? fmaxf(a22.x, 0.f) : 0.f;
        r1f[f * 9 + 1 * 3 + 2] = cOK2           ? fmaxf(a22.y, 0.f) : 0.f;
        r1f[f * 9 + 2 * 3 + 2] = (rOK2 && cOK2) ? fmaxf(a2s,   0.f) : 0.f;
    }

    // ---- write own row (c = lane) of R1h as f16: 48 halves (45 + 3 zero) ----
    {
        _Float16 rh[48];
        #pragma unroll
        for (int q = 0; q < 45; ++q) rh[q] = (_Float16)r1f[q];
        rh[45] = (_Float16)0; rh[46] = (_Float16)0; rh[47] = (_Float16)0;
        #pragma unroll
        for (int s = 0; s < 12; ++s)
            *(half4v*)&R1h[lane * R1S + s * 4] = *(const half4v*)&rh[s * 4];
    }

    const half8v zf = { (_Float16)0, (_Float16)0, (_Float16)0, (_Float16)0,
                        (_Float16)0, (_Float16)0, (_Float16)0, (_Float16)0 };

    // ---- W2 B-frags (col = r16 = g-out, k = 8*g + j within chunk), one-time ----
    half8v wb[2];
    #pragma unroll
    for (int kc = 0; kc < 2; ++kc) {
        half8v t = zf;
        #pragma unroll
        for (int j = 0; j < 8; ++j) {
            const int q = kc * 32 + g * 8 + j;
            if (r16 < 10 && q < 45)
                t[j] = (_Float16)w2[r16 * 45 + q];
        }
        wb[kc] = t;
    }

    // ---- conv2 via MFMA: D[c][gout] = sum_q R1[c][q] * W2t[q][gout] ----
    f32x4 tacc[4];
    #pragma unroll
    for (int Mt = 0; Mt < 4; ++Mt) {
        const int arow = Mt * 16 + r16;
        const half4v a0 = *(const half4v*)&R1h[arow * R1S + g * 8];
        const half4v a1 = *(const half4v*)&R1h[arow * R1S + g * 8 + 4];
        const half8v fA0 = __builtin_shufflevector(a0, a1, 0, 1, 2, 3, 4, 5, 6, 7);
        half8v fA1 = zf;
        if (g < 2) {
            const half4v c0 = *(const half4v*)&R1h[arow * R1S + 32 + g * 8];
            const half4v c1 = *(const half4v*)&R1h[arow * R1S + 32 + g * 8 + 4];
            fA1 = __builtin_shufflevector(c0, c1, 0, 1, 2, 3, 4, 5, 6, 7);
        }
        f32x4 acc = __builtin_amdgcn_mfma_f32_16x16x32_f16(
            fA0, wb[0], (f32x4){0.f, 0.f, 0.f, 0.f}, 0, 0, 0);
        acc = __builtin_amdgcn_mfma_f32_16x16x32_f16(fA1, wb[1], acc, 0, 0, 0);
        tacc[Mt] = acc;
    }

    // ---- bias + reshape-scramble scatter from D layout, division-light ----
    if (r16 < 10) {
        const float bias = b2[r16];
        const int k0 = r16 * 64 + g * 4;
        const int q0 = k0 / 10;
        const int r0 = k0 % 10;
        const int base = q0 * MROW + r0;
        #pragma unroll
        for (int Mt = 0; Mt < 4; ++Mt)
            #pragma unroll
            for (int j = 0; j < 4; ++j) {
                const int off = Mt * 16 + j;            // compile-time
                const int a = off / 10, t = off % 10;   // compile-time
                const int wrap = (r0 >= 10 - t) ? 1 : 0;
                const int addr = base + a * MROW + t + wrap * (MROW - 10);
                Mh[addr] = (_Float16)(tacc[Mt][j] + bias);
            }
    }
    // zero K-pad halves 10..15 of each M row (after R1h fully consumed)
    {
        unsigned* MhW = (unsigned*)Mh;
        MhW[lane * (MROW / 2) + 5] = 0u;
        MhW[lane * (MROW / 2) + 6] = 0u;
        MhW[lane * (MROW / 2) + 7] = 0u;
    }

    // ---- gram fragments from Mh ----
    half8v fa[4];
    #pragma unroll
    for (int T = 0; T < 4; ++T) {
        const int base = (T * 16 + r16) * MROW + (g & 1) * 8;
        const half4v lo = *(const half4v*)&Mh[base];
        const half4v hi = *(const half4v*)&Mh[base + 4];
        const half8v f = __builtin_shufflevector(lo, hi, 0, 1, 2, 3, 4, 5, 6, 7);
        fa[T] = (g < 2) ? f : zf;
    }

    // pv at this lane's cols: pvf[R][j] = pv[16R + 4g + j]
    f32x4 pvf[4];
    #pragma unroll
    for (int R = 0; R < 4; ++R)
        pvf[R] = *(const f32x4*)&pvt[lw * 64 + R * 16 + g * 4];

    // ---- per-C streaming gram + constant-shift softmax + PV ----
    const float nmc = -30.0f * L2E;
    float oval = 0.f;
    #pragma unroll
    for (int C = 0; C < 4; ++C) {
        f32x4 accC[4];
        #pragma unroll
        for (int R = 0; R < 4; ++R)
            accC[R] = __builtin_amdgcn_mfma_f32_16x16x32_f16(
                fa[R], fa[C], (f32x4){0.f, 0.f, 0.f, 0.f}, 0, 0, 0);

        f32x2 s2 = { 0.f, 0.f }, d2 = { 0.f, 0.f };
        #pragma unroll
        for (int R = 0; R < 4; ++R) {
            const float e0 = __builtin_amdgcn_exp2f(fmaf(accC[R][0], L2E, nmc));
            const float e1 = __builtin_amdgcn_exp2f(fmaf(accC[R][1], L2E, nmc));
            const float e2 = __builtin_amdgcn_exp2f(fmaf(accC[R][2], L2E, nmc));
            const float e3 = __builtin_amdgcn_exp2f(fmaf(accC[R][3], L2E, nmc));
            const f32x2 elo = { e0, e1 }, ehi = { e2, e3 };
            const f32x2 plo = { pvf[R][0], pvf[R][1] };
            const f32x2 phi = { pvf[R][2], pvf[R][3] };
            s2 += elo;
            s2 += ehi;
            d2 = __builtin_elementwise_fma(elo, plo, d2);
            d2 = __builtin_elementwise_fma(ehi, phi, d2);
        }
        float s = s2.x + s2.y;
        float d = d2.x + d2.y;
        s += __shfl_xor(s, 16);
        s += __shfl_xor(s, 32);
        d += __shfl_xor(d, 16);
        d += __shfl_xor(d, 32);
        if (g == C) oval = d / s;   // kept row 16C + r16 == lane
    }
    outs[lane * 5 + lw] = oval;

    __syncthreads();   // outs columns come from all waves

    // ---- output write: [64][4] tile -> out[b, c, h, w0..w0+3] ----
    if (tid < 64) {
        float4 v;
        v.x = outs[tid * 5 + 0];
        v.y = outs[tid * 5 + 1];
        v.z = outs[tid * 5 + 2];
        v.w = outs[tid * 5 + 3];
        *(float4*)&out[b * CHW + tid * HW + h * Wn + w0] = v;
    }
}

extern "C" void kernel_launch(void* const* d_in, const int* in_sizes, int n_in,
                              void* d_out, int out_size, void* d_ws, size_t ws_size,
                              hipStream_t stream) {
    const float* x  = (const float*)d_in[0];
    const float* pv = (const float*)d_in[1];
    const float* w1 = (const float*)d_in[2];
    const float* b1 = (const float*)d_in[3];
    const float* w2 = (const float*)d_in[4];
    const float* b2 = (const float*)d_in[5];
    float* out = (float*)d_out;

    dim3 grid(Bn * Hn * (Wn / TW));   // 4096
    dim3 block(256);
    hipLaunchKernelGGL(cam_fused_kernel, grid, block, 0, stream,
                       x, pv, w1, b1, w2, b2, out);
}